// Round 22
// baseline (716.027 us; speedup 1.0000x reference)
//
#include <hip/hip_runtime.h>
#include <stdint.h>

// f32 forward of bin_weight exactly as the reference computes it:
// q = 0.1f*sign(w); return w + (q - w), each op IEEE f32.
__device__ __forceinline__ float dance(float w) {
  float q = w > 0.f ? 0.1f : (w < 0.f ? -0.1f : 0.0f);
  float r = __fsub_rn(q, w);
  return __fadd_rn(w, r);
}

__device__ __forceinline__ int sgn(float u) {
  return u > 0.f ? 1 : (u < 0.f ? -1 : 0);
}

// transpose+dance: w[oc][k] -> out[k][oc]
__global__ void pack_dance_T(const float* __restrict__ w, float* __restrict__ out,
                             int OC, int K) {
  int idx = blockIdx.x * 256 + threadIdx.x;
  if (idx >= OC * K) return;
  int oc = idx / K, k = idx - oc * K;
  out[(size_t)k * OC + oc] = dance(w[idx]);
}

// pack convN weights: w[oc][k] -> out[k/12][oc][k%12] (48B/oc-group, float4-friendly)
__global__ void pack_dance_W12(const float* __restrict__ w, float* __restrict__ out,
                               int OC, int K) {
  int idx = blockIdx.x * 256 + threadIdx.x;
  if (idx >= OC * K) return;
  int oc = idx / K, k = idx - oc * K;
  out[((size_t)(k / 12) * OC + oc) * 12 + (k % 12)] = dance(w[idx]);
}

// pack emb weights: w[oc][k] -> out[k/4][oc][k%4], OUTPUT-index-major
__global__ void pack_dance_E4(const float* __restrict__ w, float* __restrict__ out,
                              int OC, int K) {
  int idx = blockIdx.x * 256 + threadIdx.x;   // flat OUTPUT index
  if (idx >= OC * K) return;
  int r = idx >> 2;          // = k4*OC + oc
  int lo = idx & 3;
  int oc = r % OC;
  int k4 = r / OC;
  out[idx] = dance(w[(size_t)oc * K + k4 * 4 + lo]);
}

// ---------------- conv1: scalar-pipe x-reads, f32 output ----------------
// Chain (b,tp,g,oc): z = seq FMA k=0..79, bit-identical to the round-4 PASS order.
__global__ __launch_bounds__(128) void conv1_fast(
    const float* __restrict__ x, const float* __restrict__ w1t,
    const float* __restrict__ b1, const float* __restrict__ s1,
    const float* __restrict__ o1, float* __restrict__ a1f) {
  const int tid = threadIdx.x;               // oc
  const int tp0 = blockIdx.x * 2;            // 498 groups (995 -> clamp tail)
  const int b0 = blockIdx.y * 2;
  float wreg[80];
#pragma unroll
  for (int k = 0; k < 80; ++k) wreg[k] = w1t[k * 128 + tid];

  const int sb0 = 4 * (min(tp0 + 0, 994) - tp0);
  const int sb1 = 4 * (min(tp0 + 1, 994) - tp0);
  const float4* xb0 = (const float4*)(x + (size_t)(b0 + 0) * 16000 + 16 * tp0);
  const float4* xb1 = (const float4*)(x + (size_t)(b0 + 1) * 16000 + 16 * tp0);
  float z[2][2][4] = {};
#pragma unroll
  for (int q = 0; q < 20; ++q) {
#pragma unroll
    for (int nb = 0; nb < 2; ++nb) {
      const float4* x4 = nb ? xb1 : xb0;
#pragma unroll
      for (int p = 0; p < 2; ++p) {
        const int sb = p ? sb1 : sb0;
        float4 v0 = x4[sb + q + 0];          // uniform -> scalar loads
        float4 v1 = x4[sb + q + 1];
        float4 v2 = x4[sb + q + 2];
        float4 v3 = x4[sb + q + 3];
        float4 vv[4] = {v0, v1, v2, v3};
#pragma unroll
        for (int g = 0; g < 4; ++g) {
          float zz = z[nb][p][g];
          zz = __builtin_fmaf(wreg[4 * q + 0], vv[g].x, zz);
          zz = __builtin_fmaf(wreg[4 * q + 1], vv[g].y, zz);
          zz = __builtin_fmaf(wreg[4 * q + 2], vv[g].z, zz);
          zz = __builtin_fmaf(wreg[4 * q + 3], vv[g].w, zz);
          z[nb][p][g] = zz;
        }
      }
    }
  }
  const float bv = b1[tid], sv = s1[tid], ov = o1[tid];
#pragma unroll
  for (int nb = 0; nb < 2; ++nb)
#pragma unroll
    for (int p = 0; p < 2; ++p) {
      int m = -2;
#pragma unroll
      for (int g = 0; g < 4; ++g) {
        float y = __fadd_rn(z[nb][p][g], bv);
        float t2 = __fmul_rn(y, sv);
        float u = __fadd_rn(t2, ov);
        m = max(m, sgn(u));
      }
      int tpc = min(tp0 + p, 994);
      a1f[((size_t)(b0 + nb) * 995 + tpc) * 128 + tid] = (float)m;
    }
}

// ---------------- convS (KW=3): zero-LDS, scalar-pipe f32 activations ----------------
// Chain (b,tp,g,oc): z = seq FMA over k = i*3+h ascending (ii outer, h inner) ->
// bit-identical order. Block = LANES threads, all lanes share the tp-range -> every
// activation address is block-uniform -> s_load_dwordx4 (constant cache, no LDS).
// Weights per-lane coalesced float4 from [k12][oc][12] pack.
template <int CIN, int COUT, int NOC, int NTP, bool OUTF>
__global__ __launch_bounds__(COUT / NOC) void convS(
    const float* __restrict__ ainf, const float* __restrict__ wt,
    const float* __restrict__ bias, const float* __restrict__ bns,
    const float* __restrict__ bno, float* __restrict__ aout,
    int Tin, int TPout) {
  constexpr int LANES = COUT / NOC;
  const int ocl = threadIdx.x;               // 0..LANES-1
  const int tp0 = blockIdx.x * NTP;
  const int b = blockIdx.y;
  const float* arow = ainf + (size_t)b * Tin * CIN;

  float z[NOC][NTP][4] = {};
#pragma unroll 2
  for (int i = 0; i < CIN; i += 4) {
    const int i4 = i >> 2;
    float wf[NOC][12];                       // wf[j][3*ii+h] = w k=12*i4+3*ii+h
#pragma unroll
    for (int j = 0; j < NOC; ++j) {
      const float* wp = wt + ((size_t)i4 * COUT + (ocl + j * LANES)) * 12;
      *(float4*)(wf[j] + 0) = *(const float4*)(wp + 0);
      *(float4*)(wf[j] + 4) = *(const float4*)(wp + 4);
      *(float4*)(wf[j] + 8) = *(const float4*)(wp + 8);
    }
#pragma unroll
    for (int p = 0; p < NTP; ++p) {
      float r6[6][4];
#pragma unroll
      for (int r = 0; r < 6; ++r) {
        const int gr = min(4 * tp0 + 4 * p + r, Tin - 1);  // uniform
        *(float4*)r6[r] = *(const float4*)&arow[(size_t)gr * CIN + i];
      }
#pragma unroll
      for (int j = 0; j < NOC; ++j)
#pragma unroll
        for (int g = 0; g < 4; ++g) {
          float zz = z[j][p][g];
#pragma unroll
          for (int ii = 0; ii < 4; ++ii) {
            zz = __builtin_fmaf(wf[j][ii * 3 + 0], r6[g + 0][ii], zz);
            zz = __builtin_fmaf(wf[j][ii * 3 + 1], r6[g + 1][ii], zz);
            zz = __builtin_fmaf(wf[j][ii * 3 + 2], r6[g + 2][ii], zz);
          }
          z[j][p][g] = zz;
        }
    }
  }
#pragma unroll
  for (int j = 0; j < NOC; ++j) {
    const int oc = ocl + j * LANES;
    const float bv = bias[oc], sv = bns[oc], ov = bno[oc];
#pragma unroll
    for (int p = 0; p < NTP; ++p) {
      const int tp = tp0 + p;
      if (tp < TPout) {
        int m = -2;
#pragma unroll
        for (int g = 0; g < 4; ++g) {
          float y = __fadd_rn(z[j][p][g], bv);
          float t2 = __fmul_rn(y, sv);
          float u = __fadd_rn(t2, ov);
          m = max(m, sgn(u));
        }
        if (OUTF)  // [b][oc][tp] for emb's flat-k streams
          aout[(size_t)b * (TPout * COUT) + (size_t)oc * TPout + tp] = (float)m;
        else       // [b][tp][oc] f32
          aout[((size_t)b * TPout + tp) * COUT + oc] = (float)m;
      }
    }
  }
}

// ---------------- emb v5: 1 chain/thread (max TLP), float4 weights, acts in LDS ----------------
__global__ __launch_bounds__(256) void emb_v5(
    const float* __restrict__ a4f, const float* __restrict__ wE4,
    const float* __restrict__ bemb, float* __restrict__ yemb) {
  __shared__ __align__(16) float av[7168];         // 28 KB: activation row for this b
  const int tid = threadIdx.x;
  const int oc = blockIdx.x * 256 + tid;           // grid.x=2 -> 0..511
  const int b = blockIdx.y;                        // grid.y=128
  const float* arow = a4f + (size_t)b * 7168;
  for (int i = tid * 4; i < 7168; i += 1024)       // 7 float4 per thread
    *(float4*)&av[i] = *(const float4*)(arow + i);
  __syncthreads();
  const float4* wp = (const float4*)wE4 + oc;      // [k4][512] float4, lane-contiguous
  float z = 0.f;
#pragma unroll 8
  for (int k4 = 0; k4 < 1792; ++k4) {
    const float4 w4 = wp[(size_t)k4 * 512];        // 1KB/wave coalesced
    const float4 v = *(const float4*)&av[k4 * 4];  // LDS broadcast (uniform addr)
    z = __builtin_fmaf(w4.x, v.x, z);
    z = __builtin_fmaf(w4.y, v.y, z);
    z = __builtin_fmaf(w4.z, v.z, z);
    z = __builtin_fmaf(w4.w, v.w, z);
  }
  yemb[(size_t)b * 512 + oc] = __fadd_rn(z, bemb[oc]);
}

// ---------------- fc1 + bn + sign + fc2 ----------------
__global__ __launch_bounds__(256) void fc_np(
    const float* __restrict__ yemb, const float* __restrict__ w1t,
    const float* __restrict__ s1, const float* __restrict__ o1,
    const float* __restrict__ w2t, float* __restrict__ out) {
  __shared__ float ys[512];
  __shared__ float a5[256];
  const int b = blockIdx.x;
  const int tid = threadIdx.x;
  for (int i = tid; i < 512; i += 256) ys[i] = yemb[(size_t)b * 512 + i];
  __syncthreads();
  float z = 0.f;
  for (int k = 0; k < 512; ++k)
    z = __builtin_fmaf(w1t[k * 256 + tid], ys[k], z);
  float t = __fmul_rn(z, s1[tid]);
  float u = __fadd_rn(t, o1[tid]);
  a5[tid] = u > 0.f ? 1.f : (u < 0.f ? -1.f : 0.f);
  __syncthreads();
  if (tid < 35) {
    float z2 = 0.f;
    for (int k = 0; k < 256; ++k)
      z2 = __builtin_fmaf(w2t[k * 35 + tid], a5[k], z2);
    out[(size_t)b * 35 + tid] = z2;
  }
}

extern "C" void kernel_launch(void* const* d_in, const int* in_sizes, int n_in,
                              void* d_out, int out_size, void* d_ws, size_t ws_size,
                              hipStream_t stream) {
  const float* x    = (const float*)d_in[0];
  const float* w1   = (const float*)d_in[1];
  const float* b1   = (const float*)d_in[2];
  const float* bn1s = (const float*)d_in[3];
  const float* bn1b = (const float*)d_in[4];
  const float* w2   = (const float*)d_in[5];
  const float* b2   = (const float*)d_in[6];
  const float* bn2s = (const float*)d_in[7];
  const float* bn2b = (const float*)d_in[8];
  const float* w3   = (const float*)d_in[9];
  const float* b3   = (const float*)d_in[10];
  const float* bn3s = (const float*)d_in[11];
  const float* bn3b = (const float*)d_in[12];
  const float* w5   = (const float*)d_in[13];
  const float* b5   = (const float*)d_in[14];
  const float* bn5s = (const float*)d_in[15];
  const float* bn5b = (const float*)d_in[16];
  const float* wemb = (const float*)d_in[17];
  const float* bemb = (const float*)d_in[18];
  const float* wfc1 = (const float*)d_in[19];
  const float* fc1s = (const float*)d_in[20];
  const float* fc1b = (const float*)d_in[21];
  const float* wfc2 = (const float*)d_in[22];
  float* out = (float*)d_out;

  uint8_t* ws = (uint8_t*)d_ws;
  size_t off = 0;
  auto carve = [&](size_t bytes) {
    void* p = ws + off;
    off = (off + bytes + 255) & ~(size_t)255;
    return p;
  };
  // a1f region (65.2 MB) is dead after conv2 -> a3f and a4f alias into it.
  float* a1f   = (float*)carve((size_t)128 * 995 * 128 * 4);
  float* a3f   = a1f;                                          // 8.0 MB (conv3 out)
  float* a4f   = a1f + (size_t)128 * 61 * 256 + 64;            // 14.7 MB (conv5 out)
  float* a2f   = (float*)carve((size_t)128 * 248 * 128 * 4);   // 16.3 MB
  float* yemb  = (float*)carve((size_t)128 * 512 * 4);
  float* w1t   = (float*)carve((size_t)80 * 128 * 4);          // [k][oc]
  float* wt2   = (float*)carve((size_t)384 * 128 * 4);         // [k12][oc][12]
  float* wt3   = (float*)carve((size_t)384 * 256 * 4);
  float* wt5   = (float*)carve((size_t)768 * 512 * 4);
  float* wE4   = (float*)carve((size_t)7168 * 512 * 4);        // [k4][oc][4]
  float* fc1t  = (float*)carve((size_t)512 * 256 * 4);         // [k][oc]
  float* fc2t  = (float*)carve((size_t)256 * 35 * 4);

  pack_dance_T<<<dim3((128 * 80 + 255) / 256), 256, 0, stream>>>(w1, w1t, 128, 80);
  pack_dance_W12<<<dim3((128 * 384 + 255) / 256), 256, 0, stream>>>(w2, wt2, 128, 384);
  pack_dance_W12<<<dim3((256 * 384 + 255) / 256), 256, 0, stream>>>(w3, wt3, 256, 384);
  pack_dance_W12<<<dim3((512 * 768 + 255) / 256), 256, 0, stream>>>(w5, wt5, 512, 768);
  pack_dance_E4<<<dim3((512 * 7168 + 255) / 256), 256, 0, stream>>>(wemb, wE4, 512, 7168);
  pack_dance_T<<<dim3((256 * 512 + 255) / 256), 256, 0, stream>>>(wfc1, fc1t, 256, 512);
  pack_dance_T<<<dim3((35 * 256 + 255) / 256), 256, 0, stream>>>(wfc2, fc2t, 35, 256);

  // conv1: scalar-pipe x reads, f32 output
  conv1_fast<<<dim3(498, 64), 128, 0, stream>>>(x, w1t, b1, bn1s, bn1b, a1f);

  // conv2: NOC2 LANES64 NTP2 -> grid(124,128), 64 thr, zero LDS
  convS<128, 128, 2, 2, false><<<dim3(124, 128), 64, 0, stream>>>(
      a1f, wt2, b2, bn2s, bn2b, a2f, 995, 248);
  // conv3: NOC4 LANES64 NTP2 -> grid(31,128), 64 thr, zero LDS
  convS<128, 256, 4, 2, false><<<dim3(31, 128), 64, 0, stream>>>(
      a2f, wt3, b3, bn3s, bn3b, a3f, 248, 61);
  // conv5: NOC4 LANES128 NTP1 -> grid(14,128), 128 thr, zero LDS, [b][oc][tp] out
  convS<256, 512, 4, 1, true><<<dim3(14, 128), 128, 0, stream>>>(
      a3f, wt5, b5, bn5s, bn5b, a4f, 61, 14);

  // emb: grid(2,128) x 256 thr -> 65536 threads, 1 chain each (max TLP)
  emb_v5<<<dim3(2, 128), 256, 0, stream>>>(a4f, wE4, bemb, yemb);

  fc_np<<<dim3(128), 256, 0, stream>>>(yemb, fc1t, fc1s, fc1b, fc2t, out);
}

// Round 23
// 671.120 us; speedup vs baseline: 1.0669x; 1.0669x over previous
//
#include <hip/hip_runtime.h>
#include <stdint.h>

// f32 forward of bin_weight exactly as the reference computes it:
// q = 0.1f*sign(w); return w + (q - w), each op IEEE f32.
__device__ __forceinline__ float dance(float w) {
  float q = w > 0.f ? 0.1f : (w < 0.f ? -0.1f : 0.0f);
  float r = __fsub_rn(q, w);
  return __fadd_rn(w, r);
}

__device__ __forceinline__ int sgn(float u) {
  return u > 0.f ? 1 : (u < 0.f ? -1 : 0);
}

// transpose+dance: w[oc][k] -> out[k][oc]
__global__ void pack_dance_T(const float* __restrict__ w, float* __restrict__ out,
                             int OC, int K) {
  int idx = blockIdx.x * 256 + threadIdx.x;
  if (idx >= OC * K) return;
  int oc = idx / K, k = idx - oc * K;
  out[(size_t)k * OC + oc] = dance(w[idx]);
}

// pack convN weights: w[oc][k] -> out[k/12][oc][k%12] (48B/oc-group, float4-friendly)
__global__ void pack_dance_W12(const float* __restrict__ w, float* __restrict__ out,
                               int OC, int K) {
  int idx = blockIdx.x * 256 + threadIdx.x;
  if (idx >= OC * K) return;
  int oc = idx / K, k = idx - oc * K;
  out[((size_t)(k / 12) * OC + oc) * 12 + (k % 12)] = dance(w[idx]);
}

// pack emb weights: w[oc][k] -> out[k/4][oc][k%4], OUTPUT-index-major
__global__ void pack_dance_E4(const float* __restrict__ w, float* __restrict__ out,
                              int OC, int K) {
  int idx = blockIdx.x * 256 + threadIdx.x;   // flat OUTPUT index
  if (idx >= OC * K) return;
  int r = idx >> 2;          // = k4*OC + oc
  int lo = idx & 3;
  int oc = r % OC;
  int k4 = r / OC;
  out[idx] = dance(w[(size_t)oc * K + k4 * 4 + lo]);
}

// ---------------- conv1: scalar-pipe x-reads, int8 output (r21 form) ----------------
// Chain (b,tp,g,oc): z = seq FMA k=0..79, bit-identical to the round-4 PASS order.
__global__ __launch_bounds__(128) void conv1_fast(
    const float* __restrict__ x, const float* __restrict__ w1t,
    const float* __restrict__ b1, const float* __restrict__ s1,
    const float* __restrict__ o1, int8_t* __restrict__ a1) {
  const int tid = threadIdx.x;               // oc
  const int tp0 = blockIdx.x * 2;            // 498 groups (995 -> clamp tail)
  const int b0 = blockIdx.y * 2;
  float wreg[80];
#pragma unroll
  for (int k = 0; k < 80; ++k) wreg[k] = w1t[k * 128 + tid];

  const int sb0 = 4 * (min(tp0 + 0, 994) - tp0);
  const int sb1 = 4 * (min(tp0 + 1, 994) - tp0);
  const float4* xb0 = (const float4*)(x + (size_t)(b0 + 0) * 16000 + 16 * tp0);
  const float4* xb1 = (const float4*)(x + (size_t)(b0 + 1) * 16000 + 16 * tp0);
  float z[2][2][4] = {};
#pragma unroll
  for (int q = 0; q < 20; ++q) {
#pragma unroll
    for (int nb = 0; nb < 2; ++nb) {
      const float4* x4 = nb ? xb1 : xb0;
#pragma unroll
      for (int p = 0; p < 2; ++p) {
        const int sb = p ? sb1 : sb0;
        float4 v0 = x4[sb + q + 0];          // uniform -> scalar loads
        float4 v1 = x4[sb + q + 1];
        float4 v2 = x4[sb + q + 2];
        float4 v3 = x4[sb + q + 3];
        float4 vv[4] = {v0, v1, v2, v3};
#pragma unroll
        for (int g = 0; g < 4; ++g) {
          float zz = z[nb][p][g];
          zz = __builtin_fmaf(wreg[4 * q + 0], vv[g].x, zz);
          zz = __builtin_fmaf(wreg[4 * q + 1], vv[g].y, zz);
          zz = __builtin_fmaf(wreg[4 * q + 2], vv[g].z, zz);
          zz = __builtin_fmaf(wreg[4 * q + 3], vv[g].w, zz);
          z[nb][p][g] = zz;
        }
      }
    }
  }
  const float bv = b1[tid], sv = s1[tid], ov = o1[tid];
#pragma unroll
  for (int nb = 0; nb < 2; ++nb)
#pragma unroll
    for (int p = 0; p < 2; ++p) {
      int m = -2;
#pragma unroll
      for (int g = 0; g < 4; ++g) {
        float y = __fadd_rn(z[nb][p][g], bv);
        float t2 = __fmul_rn(y, sv);
        float u = __fadd_rn(t2, ov);
        m = max(m, sgn(u));
      }
      int tpc = min(tp0 + p, 994);
      a1[((size_t)(b0 + nb) * 995 + tpc) * 128 + tid] = (int8_t)m;
    }
}

// ---------------- conv2: int8-LDS convN (r21's 204us config), f32 output ----------------
// Chain (b,tp,g,oc): z = seq FMA over k = i*3+h ascending (ii outer, h inner).
template <int CIN, int COUT, int NOC, int TY, int NTP, int NB>
__global__ __launch_bounds__((COUT / NOC) * TY) void convN_fast(
    const int8_t* __restrict__ ain, const float* __restrict__ wt,
    const float* __restrict__ bias, const float* __restrict__ bns,
    const float* __restrict__ bno, float* __restrict__ aoutf,
    int Tin, int TPout) {
  constexpr int LANES = COUT / NOC;
  constexpr int ROWS = 4 * TY * NTP + 2;
  constexpr int NT = LANES * TY;
  __shared__ __align__(16) float as_[NB][ROWS][CIN];
  const int tid = threadIdx.x;
  const int ocl = tid % LANES;
  const int ty = tid / LANES;
  const int tp0 = blockIdx.x * (TY * NTP);
  const int b0 = blockIdx.y * NB;
  for (int t = tid; t < NB * ROWS * CIN; t += NT) {
    int nb = t / (ROWS * CIN);
    int rem = t - nb * (ROWS * CIN);
    int r = rem / CIN, c = rem - r * CIN;
    int gr = min(4 * tp0 + r, Tin - 1);
    as_[nb][r][c] = (float)ain[((size_t)(b0 + nb) * Tin + gr) * CIN + c];
  }
  __syncthreads();

  float z[NOC][NB][NTP][4] = {};
#pragma unroll 2
  for (int i = 0; i < CIN; i += 4) {
    const int i4 = i >> 2;
    float wf[NOC][12];                       // wf[j][3*ii+h] = w k=12*i4+3*ii+h
#pragma unroll
    for (int j = 0; j < NOC; ++j) {
      const float* wp = wt + ((size_t)i4 * COUT + (ocl + j * LANES)) * 12;
      *(float4*)(wf[j] + 0) = *(const float4*)(wp + 0);
      *(float4*)(wf[j] + 4) = *(const float4*)(wp + 4);
      *(float4*)(wf[j] + 8) = *(const float4*)(wp + 8);
    }
#pragma unroll
    for (int nb = 0; nb < NB; ++nb)
#pragma unroll
      for (int p = 0; p < NTP; ++p) {
        const int rbase = 4 * (NTP * ty + p);
        float r6[6][4];
#pragma unroll
        for (int r = 0; r < 6; ++r)
          *(float4*)r6[r] = *(const float4*)&as_[nb][rbase + r][i];
#pragma unroll
        for (int j = 0; j < NOC; ++j)
#pragma unroll
          for (int g = 0; g < 4; ++g) {
            float zz = z[j][nb][p][g];
#pragma unroll
            for (int ii = 0; ii < 4; ++ii) {
              zz = __builtin_fmaf(wf[j][ii * 3 + 0], r6[g + 0][ii], zz);
              zz = __builtin_fmaf(wf[j][ii * 3 + 1], r6[g + 1][ii], zz);
              zz = __builtin_fmaf(wf[j][ii * 3 + 2], r6[g + 2][ii], zz);
            }
            z[j][nb][p][g] = zz;
          }
      }
  }
#pragma unroll
  for (int j = 0; j < NOC; ++j) {
    const int oc = ocl + j * LANES;
    const float bv = bias[oc], sv = bns[oc], ov = bno[oc];
#pragma unroll
    for (int nb = 0; nb < NB; ++nb)
#pragma unroll
      for (int p = 0; p < NTP; ++p) {
        const int tp = tp0 + NTP * ty + p;
        if (tp < TPout) {
          int m = -2;
#pragma unroll
          for (int g = 0; g < 4; ++g) {
            float y = __fadd_rn(z[j][nb][p][g], bv);
            float t2 = __fmul_rn(y, sv);
            float u = __fadd_rn(t2, ov);
            m = max(m, sgn(u));
          }
          aoutf[((size_t)(b0 + nb) * TPout + tp) * COUT + oc] = (float)m;
        }
      }
  }
}

// ---------------- convS (KW=3): zero-LDS, scalar-pipe f32 activations (r22) ----------------
// Chain (b,tp,g,oc): z = seq FMA over k = i*3+h ascending -> bit-identical order.
template <int CIN, int COUT, int NOC, int NTP, bool OUTF>
__global__ __launch_bounds__(COUT / NOC) void convS(
    const float* __restrict__ ainf, const float* __restrict__ wt,
    const float* __restrict__ bias, const float* __restrict__ bns,
    const float* __restrict__ bno, float* __restrict__ aout,
    int Tin, int TPout) {
  constexpr int LANES = COUT / NOC;
  const int ocl = threadIdx.x;               // 0..LANES-1
  const int tp0 = blockIdx.x * NTP;
  const int b = blockIdx.y;
  const float* arow = ainf + (size_t)b * Tin * CIN;

  float z[NOC][NTP][4] = {};
#pragma unroll 2
  for (int i = 0; i < CIN; i += 4) {
    const int i4 = i >> 2;
    float wf[NOC][12];
#pragma unroll
    for (int j = 0; j < NOC; ++j) {
      const float* wp = wt + ((size_t)i4 * COUT + (ocl + j * LANES)) * 12;
      *(float4*)(wf[j] + 0) = *(const float4*)(wp + 0);
      *(float4*)(wf[j] + 4) = *(const float4*)(wp + 4);
      *(float4*)(wf[j] + 8) = *(const float4*)(wp + 8);
    }
#pragma unroll
    for (int p = 0; p < NTP; ++p) {
      float r6[6][4];
#pragma unroll
      for (int r = 0; r < 6; ++r) {
        const int gr = min(4 * tp0 + 4 * p + r, Tin - 1);  // uniform
        *(float4*)r6[r] = *(const float4*)&arow[(size_t)gr * CIN + i];
      }
#pragma unroll
      for (int j = 0; j < NOC; ++j)
#pragma unroll
        for (int g = 0; g < 4; ++g) {
          float zz = z[j][p][g];
#pragma unroll
          for (int ii = 0; ii < 4; ++ii) {
            zz = __builtin_fmaf(wf[j][ii * 3 + 0], r6[g + 0][ii], zz);
            zz = __builtin_fmaf(wf[j][ii * 3 + 1], r6[g + 1][ii], zz);
            zz = __builtin_fmaf(wf[j][ii * 3 + 2], r6[g + 2][ii], zz);
          }
          z[j][p][g] = zz;
        }
    }
  }
#pragma unroll
  for (int j = 0; j < NOC; ++j) {
    const int oc = ocl + j * LANES;
    const float bv = bias[oc], sv = bns[oc], ov = bno[oc];
#pragma unroll
    for (int p = 0; p < NTP; ++p) {
      const int tp = tp0 + p;
      if (tp < TPout) {
        int m = -2;
#pragma unroll
        for (int g = 0; g < 4; ++g) {
          float y = __fadd_rn(z[j][p][g], bv);
          float t2 = __fmul_rn(y, sv);
          float u = __fadd_rn(t2, ov);
          m = max(m, sgn(u));
        }
        if (OUTF)  // [b][oc][tp] for emb's flat-k streams
          aout[(size_t)b * (TPout * COUT) + (size_t)oc * TPout + tp] = (float)m;
        else       // [b][tp][oc] f32
          aout[((size_t)b * TPout + tp) * COUT + oc] = (float)m;
      }
    }
  }
}

// ---------------- emb v5: 1 chain/thread (max TLP), float4 weights, acts in LDS ----------------
__global__ __launch_bounds__(256) void emb_v5(
    const float* __restrict__ a4f, const float* __restrict__ wE4,
    const float* __restrict__ bemb, float* __restrict__ yemb) {
  __shared__ __align__(16) float av[7168];         // 28 KB: activation row for this b
  const int tid = threadIdx.x;
  const int oc = blockIdx.x * 256 + tid;           // grid.x=2 -> 0..511
  const int b = blockIdx.y;                        // grid.y=128
  const float* arow = a4f + (size_t)b * 7168;
  for (int i = tid * 4; i < 7168; i += 1024)       // 7 float4 per thread
    *(float4*)&av[i] = *(const float4*)(arow + i);
  __syncthreads();
  const float4* wp = (const float4*)wE4 + oc;      // [k4][512] float4, lane-contiguous
  float z = 0.f;
#pragma unroll 8
  for (int k4 = 0; k4 < 1792; ++k4) {
    const float4 w4 = wp[(size_t)k4 * 512];        // 1KB/wave coalesced
    const float4 v = *(const float4*)&av[k4 * 4];  // LDS broadcast (uniform addr)
    z = __builtin_fmaf(w4.x, v.x, z);
    z = __builtin_fmaf(w4.y, v.y, z);
    z = __builtin_fmaf(w4.z, v.z, z);
    z = __builtin_fmaf(w4.w, v.w, z);
  }
  yemb[(size_t)b * 512 + oc] = __fadd_rn(z, bemb[oc]);
}

// ---------------- fc1 + bn + sign + fc2 ----------------
__global__ __launch_bounds__(256) void fc_np(
    const float* __restrict__ yemb, const float* __restrict__ w1t,
    const float* __restrict__ s1, const float* __restrict__ o1,
    const float* __restrict__ w2t, float* __restrict__ out) {
  __shared__ float ys[512];
  __shared__ float a5[256];
  const int b = blockIdx.x;
  const int tid = threadIdx.x;
  for (int i = tid; i < 512; i += 256) ys[i] = yemb[(size_t)b * 512 + i];
  __syncthreads();
  float z = 0.f;
  for (int k = 0; k < 512; ++k)
    z = __builtin_fmaf(w1t[k * 256 + tid], ys[k], z);
  float t = __fmul_rn(z, s1[tid]);
  float u = __fadd_rn(t, o1[tid]);
  a5[tid] = u > 0.f ? 1.f : (u < 0.f ? -1.f : 0.f);
  __syncthreads();
  if (tid < 35) {
    float z2 = 0.f;
    for (int k = 0; k < 256; ++k)
      z2 = __builtin_fmaf(w2t[k * 35 + tid], a5[k], z2);
    out[(size_t)b * 35 + tid] = z2;
  }
}

extern "C" void kernel_launch(void* const* d_in, const int* in_sizes, int n_in,
                              void* d_out, int out_size, void* d_ws, size_t ws_size,
                              hipStream_t stream) {
  const float* x    = (const float*)d_in[0];
  const float* w1   = (const float*)d_in[1];
  const float* b1   = (const float*)d_in[2];
  const float* bn1s = (const float*)d_in[3];
  const float* bn1b = (const float*)d_in[4];
  const float* w2   = (const float*)d_in[5];
  const float* b2   = (const float*)d_in[6];
  const float* bn2s = (const float*)d_in[7];
  const float* bn2b = (const float*)d_in[8];
  const float* w3   = (const float*)d_in[9];
  const float* b3   = (const float*)d_in[10];
  const float* bn3s = (const float*)d_in[11];
  const float* bn3b = (const float*)d_in[12];
  const float* w5   = (const float*)d_in[13];
  const float* b5   = (const float*)d_in[14];
  const float* bn5s = (const float*)d_in[15];
  const float* bn5b = (const float*)d_in[16];
  const float* wemb = (const float*)d_in[17];
  const float* bemb = (const float*)d_in[18];
  const float* wfc1 = (const float*)d_in[19];
  const float* fc1s = (const float*)d_in[20];
  const float* fc1b = (const float*)d_in[21];
  const float* wfc2 = (const float*)d_in[22];
  float* out = (float*)d_out;

  uint8_t* ws = (uint8_t*)d_ws;
  size_t off = 0;
  auto carve = [&](size_t bytes) {
    void* p = ws + off;
    off = (off + bytes + 255) & ~(size_t)255;
    return p;
  };
  int8_t* a1   = (int8_t*)carve((size_t)128 * 995 * 128);      // 16.3 MB
  float* a2f   = (float*)carve((size_t)128 * 248 * 128 * 4);   // 16.3 MB
  float* a3f   = (float*)carve((size_t)128 * 61 * 256 * 4);    //  8.0 MB
  float* a4f   = (float*)carve((size_t)128 * 512 * 14 * 4);    // 14.7 MB [b][oc][tp]
  float* yemb  = (float*)carve((size_t)128 * 512 * 4);
  float* w1t   = (float*)carve((size_t)80 * 128 * 4);          // [k][oc]
  float* wt2   = (float*)carve((size_t)384 * 128 * 4);         // [k12][oc][12]
  float* wt3   = (float*)carve((size_t)384 * 256 * 4);
  float* wt5   = (float*)carve((size_t)768 * 512 * 4);
  float* wE4   = (float*)carve((size_t)7168 * 512 * 4);        // [k4][oc][4]
  float* fc1t  = (float*)carve((size_t)512 * 256 * 4);         // [k][oc]
  float* fc2t  = (float*)carve((size_t)256 * 35 * 4);

  pack_dance_T<<<dim3((128 * 80 + 255) / 256), 256, 0, stream>>>(w1, w1t, 128, 80);
  pack_dance_W12<<<dim3((128 * 384 + 255) / 256), 256, 0, stream>>>(w2, wt2, 128, 384);
  pack_dance_W12<<<dim3((256 * 384 + 255) / 256), 256, 0, stream>>>(w3, wt3, 256, 384);
  pack_dance_W12<<<dim3((512 * 768 + 255) / 256), 256, 0, stream>>>(w5, wt5, 512, 768);
  pack_dance_E4<<<dim3((512 * 7168 + 255) / 256), 256, 0, stream>>>(wemb, wE4, 512, 7168);
  pack_dance_T<<<dim3((256 * 512 + 255) / 256), 256, 0, stream>>>(wfc1, fc1t, 256, 512);
  pack_dance_T<<<dim3((35 * 256 + 255) / 256), 256, 0, stream>>>(wfc2, fc2t, 35, 256);

  // conv1: scalar-pipe x reads, int8 a1 out (r21 best)
  conv1_fast<<<dim3(498, 64), 128, 0, stream>>>(x, w1t, b1, bn1s, bn1b, a1);

  // conv2: int8-LDS NOC4 LANES32 TY2 NTP2 NB1 (r21's 204us config), f32 out
  convN_fast<128, 128, 4, 2, 2, 1><<<dim3(62, 128), 64, 0, stream>>>(
      a1, wt2, b2, bn2s, bn2b, a2f, 995, 248);
  // conv3: convS NOC4 LANES64 NTP2, zero LDS (r22 winner)
  convS<128, 256, 4, 2, false><<<dim3(31, 128), 64, 0, stream>>>(
      a2f, wt3, b3, bn3s, bn3b, a3f, 248, 61);
  // conv5: convS NOC4 LANES128 NTP1, zero LDS, [b][oc][tp] out (r22 winner)
  convS<256, 512, 4, 1, true><<<dim3(14, 128), 128, 0, stream>>>(
      a3f, wt5, b5, bn5s, bn5b, a4f, 61, 14);

  // emb: grid(2,128) x 256 thr -> 65536 threads, 1 chain each (max TLP)
  emb_v5<<<dim3(2, 128), 256, 0, stream>>>(a4f, wE4, bemb, yemb);

  fc_np<<<dim3(128), 256, 0, stream>>>(yemb, fc1t, fc1s, fc1b, fc2t, out);
}